// Round 1
// baseline (113.176 us; speedup 1.0000x reference)
//
#include <hip/hip_runtime.h>
#include <hip/hip_bf16.h>
#include <stdint.h>

// Problem constants: B=64, N=32, D=512, P=N*(N-1)=992, M = B*P = 63488.
// out[b,p,d] = sum_k relu(U[b,i_p,k] + V[b,j_p,k] + b1[k]) * W2[d,k] + b2[d]
// U = pf @ W1[:, :512]^T  (b1 folded in),  V = pf @ W1[:, 512:]^T

typedef __attribute__((ext_vector_type(4))) float f32x4;
typedef __attribute__((ext_vector_type(8))) short bf16x8;
typedef __attribute__((ext_vector_type(4))) unsigned int u32x4;
typedef __attribute__((ext_vector_type(2))) unsigned int u32x2;

__device__ __forceinline__ uint32_t cvt2_bf16(float a, float b) {
    __hip_bfloat162 h = __float22bfloat162_rn(make_float2(a, b));
    uint32_t u;
    __builtin_memcpy(&u, &h, 4);
    return u;
}

__device__ __forceinline__ void async_lds16(const void* g, void* l) {
    __builtin_amdgcn_global_load_lds(
        (const __attribute__((address_space(1))) void*)g,
        (__attribute__((address_space(3))) void*)l, 16, 0, 0);
}

// ---------------------------------------------------------------------------
// Kernel 1: W2 (512x512 fp32) -> bf16
// ---------------------------------------------------------------------------
__global__ __launch_bounds__(256) void w2_to_bf16(const float* __restrict__ W2,
                                                  unsigned short* __restrict__ W2b) {
    int idx = blockIdx.x * 256 + threadIdx.x;   // 65536 threads, 4 elems each
    f32x4 v = *(const f32x4*)(W2 + (size_t)idx * 4);
    u32x2 p;
    p[0] = cvt2_bf16(v[0], v[1]);
    p[1] = cvt2_bf16(v[2], v[3]);
    *(u32x2*)(W2b + (size_t)idx * 4) = p;
}

// ---------------------------------------------------------------------------
// Kernel 2: UV = pf @ [W1a^T | W1b^T]  (fp32 out, b1 folded into U half)
// M=2048 rows (b*32+n), Ncols=1024 (c<512 -> U[d=c], c>=512 -> V[d=c-512])
// Tile 64x128, BK=64, 256 threads = 4 waves (2x2), wave tile 32x64.
// ---------------------------------------------------------------------------
__global__ __launch_bounds__(256) void uv_gemm(const float* __restrict__ pf,
                                               const float* __restrict__ W1,
                                               const float* __restrict__ b1,
                                               float* __restrict__ UV) {
    __shared__ unsigned short As[64][64];
    __shared__ unsigned short Bs[128][64];

    const int t = threadIdx.x;
    const int m0 = (blockIdx.x >> 3) * 64;    // 32 row tiles
    const int c0 = (blockIdx.x & 7) * 128;    // 8 col tiles

    const int sr = t >> 2;            // 0..63
    const int sk = (t & 3) << 4;      // 0,16,32,48 (floats within BK)

    const int wave = t >> 6, lane = t & 63;
    const int wr = wave >> 1, wc = wave & 1;
    const int lr = lane & 15, lk = (lane >> 4) << 3;

    f32x4 acc[2][4] = {};

    // precomputed global row bases
    const float* a_src = pf + (size_t)(m0 + sr) * 512;
    const float* b_src[2];
#pragma unroll
    for (int pass = 0; pass < 2; ++pass) {
        int c = c0 + pass * 64 + sr;
        int d = c & 511;
        int koff = (c >> 9) * 512;
        b_src[pass] = W1 + (size_t)d * 1024 + koff;
    }

    for (int kt = 0; kt < 512; kt += 64) {
        // A tile: pf rows -> bf16
        {
            const float* gp = a_src + kt + sk;
            f32x4 x0 = ((const f32x4*)gp)[0];
            f32x4 x1 = ((const f32x4*)gp)[1];
            f32x4 x2 = ((const f32x4*)gp)[2];
            f32x4 x3 = ((const f32x4*)gp)[3];
            u32x4 P0, P1;
            P0[0] = cvt2_bf16(x0[0], x0[1]); P0[1] = cvt2_bf16(x0[2], x0[3]);
            P0[2] = cvt2_bf16(x1[0], x1[1]); P0[3] = cvt2_bf16(x1[2], x1[3]);
            P1[0] = cvt2_bf16(x2[0], x2[1]); P1[1] = cvt2_bf16(x2[2], x2[3]);
            P1[2] = cvt2_bf16(x3[0], x3[1]); P1[3] = cvt2_bf16(x3[2], x3[3]);
            u32x4* dst = (u32x4*)&As[sr][sk];
            dst[0] = P0; dst[1] = P1;
        }
        // B tile: W1 columns (as B^T rows) -> bf16
#pragma unroll
        for (int pass = 0; pass < 2; ++pass) {
            const float* gp = b_src[pass] + kt + sk;
            f32x4 x0 = ((const f32x4*)gp)[0];
            f32x4 x1 = ((const f32x4*)gp)[1];
            f32x4 x2 = ((const f32x4*)gp)[2];
            f32x4 x3 = ((const f32x4*)gp)[3];
            u32x4 P0, P1;
            P0[0] = cvt2_bf16(x0[0], x0[1]); P0[1] = cvt2_bf16(x0[2], x0[3]);
            P0[2] = cvt2_bf16(x1[0], x1[1]); P0[3] = cvt2_bf16(x1[2], x1[3]);
            P1[0] = cvt2_bf16(x2[0], x2[1]); P1[1] = cvt2_bf16(x2[2], x2[3]);
            P1[2] = cvt2_bf16(x3[0], x3[1]); P1[3] = cvt2_bf16(x3[2], x3[3]);
            u32x4* dst = (u32x4*)&Bs[pass * 64 + sr][sk];
            dst[0] = P0; dst[1] = P1;
        }
        __syncthreads();
#pragma unroll
        for (int kk = 0; kk < 2; ++kk) {
            bf16x8 af[2], bfr[4];
#pragma unroll
            for (int m = 0; m < 2; ++m)
                af[m] = *(const bf16x8*)&As[wr * 32 + m * 16 + lr][kk * 32 + lk];
#pragma unroll
            for (int n = 0; n < 4; ++n)
                bfr[n] = *(const bf16x8*)&Bs[wc * 64 + n * 16 + lr][kk * 32 + lk];
#pragma unroll
            for (int m = 0; m < 2; ++m)
#pragma unroll
                for (int n = 0; n < 4; ++n)
                    acc[m][n] = __builtin_amdgcn_mfma_f32_16x16x32_bf16(
                        af[m], bfr[n], acc[m][n], 0, 0, 0);
        }
        __syncthreads();
    }

    // epilogue: UV[row][c] = acc (+ b1 for U half)
    const int cr = lane >> 4;   // row group
    const int cc = lane & 15;   // col
#pragma unroll
    for (int m = 0; m < 2; ++m) {
#pragma unroll
        for (int n = 0; n < 4; ++n) {
            int c = c0 + wc * 64 + n * 16 + cc;
            float bias = (c < 512) ? b1[c] : 0.0f;
            int rowb = m0 + wr * 32 + m * 16 + cr * 4;
#pragma unroll
            for (int r_ = 0; r_ < 4; ++r_)
                UV[(size_t)(rowb + r_) * 1024 + c] = acc[m][n][r_] + bias;
        }
    }
}

// ---------------------------------------------------------------------------
// Kernel 3: out[m, d] = relu(U[row_i(m)] + V[row_j(m)]) @ W2^T + b2
// M = 63488, Ncols = 512, K = 512. Tile 128x128, BK=64, 256 thr = 4 waves 2x2.
// A tile built on the fly from UV (fp32) -> relu -> bf16.
// B tile (W2 bf16, already B^T layout) via global_load_lds width 16.
// ---------------------------------------------------------------------------
__global__ __launch_bounds__(256) void fused_gemm(const float* __restrict__ UV,
                                                  const unsigned short* __restrict__ W2b,
                                                  const float* __restrict__ b2,
                                                  float* __restrict__ out) {
    __shared__ unsigned short As[128][64];
    __shared__ unsigned short Bs[128][64];

    const int t = threadIdx.x;
    const int bx = blockIdx.x;
    const int c0 = (bx & 3) * 128;    // 4 col tiles
    const int m0 = (bx >> 2) * 128;   // 496 row tiles

    const int sr = t >> 2;            // 0..63
    const int sk = (t & 3) << 4;      // 0,16,32,48

    const int wave = t >> 6, lane = t & 63;
    const int wr = wave >> 1, wc = wave & 1;
    const int lr = lane & 15, lk = (lane >> 4) << 3;

    // Per-thread A-row decode (K-invariant): m -> (b, i, j)
    const float* uptr[2];
    const float* vptr[2];
#pragma unroll
    for (int pass = 0; pass < 2; ++pass) {
        int m = m0 + pass * 64 + sr;
        int b = m / 992;
        int p = m - b * 992;
        int i = p / 31;
        int r = p - i * 31;
        int j = r + (r >= i ? 1 : 0);
        uptr[pass] = UV + (size_t)(b * 32 + i) * 1024;        // U row (b1 folded)
        vptr[pass] = UV + (size_t)(b * 32 + j) * 1024 + 512;  // V row
    }

    f32x4 acc[4][4] = {};

    for (int kt = 0; kt < 512; kt += 64) {
        // B tile: 16 KB via 4 async issues (4 KB each, lane-linear)
#pragma unroll
        for (int q = 0; q < 4; ++q) {
            const unsigned short* g =
                W2b + (size_t)(c0 + q * 32 + (t >> 3)) * 512 + kt + ((t & 7) << 3);
            char* l = ((char*)&Bs[0][0]) + q * 4096 + wave * 1024;  // +lane*16 by HW
            async_lds16(g, l);
        }
        // A tile: relu(U+V) -> bf16, register path
#pragma unroll
        for (int pass = 0; pass < 2; ++pass) {
            const float* up = uptr[pass] + kt + sk;
            const float* vp = vptr[pass] + kt + sk;
            f32x4 u0 = ((const f32x4*)up)[0];
            f32x4 u1 = ((const f32x4*)up)[1];
            f32x4 u2 = ((const f32x4*)up)[2];
            f32x4 u3 = ((const f32x4*)up)[3];
            f32x4 v0 = ((const f32x4*)vp)[0];
            f32x4 v1 = ((const f32x4*)vp)[1];
            f32x4 v2 = ((const f32x4*)vp)[2];
            f32x4 v3 = ((const f32x4*)vp)[3];
            f32x4 h0, h1, h2, h3;
#pragma unroll
            for (int q = 0; q < 4; ++q) {
                h0[q] = fmaxf(u0[q] + v0[q], 0.0f);
                h1[q] = fmaxf(u1[q] + v1[q], 0.0f);
                h2[q] = fmaxf(u2[q] + v2[q], 0.0f);
                h3[q] = fmaxf(u3[q] + v3[q], 0.0f);
            }
            u32x4 P0, P1;
            P0[0] = cvt2_bf16(h0[0], h0[1]); P0[1] = cvt2_bf16(h0[2], h0[3]);
            P0[2] = cvt2_bf16(h1[0], h1[1]); P0[3] = cvt2_bf16(h1[2], h1[3]);
            P1[0] = cvt2_bf16(h2[0], h2[1]); P1[1] = cvt2_bf16(h2[2], h2[3]);
            P1[2] = cvt2_bf16(h3[0], h3[1]); P1[3] = cvt2_bf16(h3[2], h3[3]);
            u32x4* dst = (u32x4*)&As[pass * 64 + sr][sk];
            dst[0] = P0; dst[1] = P1;
        }
        __syncthreads();
#pragma unroll
        for (int kk = 0; kk < 2; ++kk) {
            bf16x8 af[4], bfr[4];
#pragma unroll
            for (int m = 0; m < 4; ++m)
                af[m] = *(const bf16x8*)&As[wr * 64 + m * 16 + lr][kk * 32 + lk];
#pragma unroll
            for (int n = 0; n < 4; ++n)
                bfr[n] = *(const bf16x8*)&Bs[wc * 64 + n * 16 + lr][kk * 32 + lk];
#pragma unroll
            for (int m = 0; m < 4; ++m)
#pragma unroll
                for (int n = 0; n < 4; ++n)
                    acc[m][n] = __builtin_amdgcn_mfma_f32_16x16x32_bf16(
                        af[m], bfr[n], acc[m][n], 0, 0, 0);
        }
        __syncthreads();
    }

    // epilogue: C/D layout col=lane&15, row=(lane>>4)*4+reg
    const int cr = lane >> 4;
    const int cc = lane & 15;
#pragma unroll
    for (int m = 0; m < 4; ++m) {
#pragma unroll
        for (int n = 0; n < 4; ++n) {
            int col = c0 + wc * 64 + n * 16 + cc;
            float bias = b2[col];
            int rowb = m0 + wr * 64 + m * 16 + cr * 4;
#pragma unroll
            for (int r_ = 0; r_ < 4; ++r_)
                out[(size_t)(rowb + r_) * 512 + col] = acc[m][n][r_] + bias;
        }
    }
}

// ---------------------------------------------------------------------------
extern "C" void kernel_launch(void* const* d_in, const int* in_sizes, int n_in,
                              void* d_out, int out_size, void* d_ws, size_t ws_size,
                              hipStream_t stream) {
    const float* pf = (const float*)d_in[0];   // (64, 32, 512)
    const float* W1 = (const float*)d_in[1];   // (512, 1024)
    const float* b1 = (const float*)d_in[2];   // (512,)
    const float* W2 = (const float*)d_in[3];   // (512, 512)
    const float* b2 = (const float*)d_in[4];   // (512,)
    float* out = (float*)d_out;                // (64, 992, 512)

    float* UV = (float*)d_ws;                                      // 2048*1024*4 = 8 MB
    unsigned short* W2b = (unsigned short*)((char*)d_ws + (size_t)8 * 1024 * 1024); // 512 KB

    w2_to_bf16<<<dim3(256), dim3(256), 0, stream>>>(W2, W2b);
    uv_gemm<<<dim3(256), dim3(256), 0, stream>>>(pf, W1, b1, UV);
    fused_gemm<<<dim3(1984), dim3(256), 0, stream>>>(UV, W2b, b2, out);
}

// Round 2
// 110.425 us; speedup vs baseline: 1.0249x; 1.0249x over previous
//
#include <hip/hip_runtime.h>
#include <hip/hip_bf16.h>
#include <stdint.h>

// Problem constants: B=64, N=32, D=512, P=N*(N-1)=992, M = B*P = 63488.
// out[b,p,d] = sum_k relu(U[b,i_p,k] + V[b,j_p,k] + b1[k]) * W2[d,k] + b2[d]
// U = pf @ W1[:, :512]^T  (b1 folded in),  V = pf @ W1[:, 512:]^T

typedef __attribute__((ext_vector_type(4))) float f32x4;
typedef __attribute__((ext_vector_type(8))) short bf16x8;
typedef __attribute__((ext_vector_type(4))) unsigned int u32x4;
typedef __attribute__((ext_vector_type(2))) unsigned int u32x2;

__device__ __forceinline__ uint32_t cvt2_bf16(float a, float b) {
    __hip_bfloat162 h = __float22bfloat162_rn(make_float2(a, b));
    uint32_t u;
    __builtin_memcpy(&u, &h, 4);
    return u;
}

__device__ __forceinline__ void async_lds16(const void* g, void* l) {
    __builtin_amdgcn_global_load_lds(
        (const __attribute__((address_space(1))) void*)g,
        (__attribute__((address_space(3))) void*)l, 16, 0, 0);
}

// ---------------------------------------------------------------------------
// Kernel 1: W2 (512x512 fp32) -> bf16
// ---------------------------------------------------------------------------
__global__ __launch_bounds__(256) void w2_to_bf16(const float* __restrict__ W2,
                                                  unsigned short* __restrict__ W2b) {
    int idx = blockIdx.x * 256 + threadIdx.x;   // 65536 threads, 4 elems each
    f32x4 v = *(const f32x4*)(W2 + (size_t)idx * 4);
    u32x2 p;
    p[0] = cvt2_bf16(v[0], v[1]);
    p[1] = cvt2_bf16(v[2], v[3]);
    *(u32x2*)(W2b + (size_t)idx * 4) = p;
}

// ---------------------------------------------------------------------------
// Kernel 2: UV = pf @ [W1a^T | W1b^T]  (fp32 out, b1 folded into U half)
// Tile 64x128, BK=64, 256 threads = 4 waves (2x2), wave tile 32x64.
// LDS tiles XOR-swizzled in 16B granules: phys_g = g ^ (row & 7).
// ---------------------------------------------------------------------------
__global__ __launch_bounds__(256) void uv_gemm(const float* __restrict__ pf,
                                               const float* __restrict__ W1,
                                               const float* __restrict__ b1,
                                               float* __restrict__ UV) {
    __shared__ unsigned short As[64][64];
    __shared__ unsigned short Bs[128][64];

    const int t = threadIdx.x;
    const int m0 = (blockIdx.x >> 3) * 64;    // 32 row tiles
    const int c0 = (blockIdx.x & 7) * 128;    // 8 col tiles

    const int sr = t >> 2;            // 0..63
    const int sk = (t & 3) << 4;      // float index within BK
    const int g0 = (t & 3) << 1;      // first 16B granule of this thread's 32B

    const int wave = t >> 6, lane = t & 63;
    const int wr = wave >> 1, wc = wave & 1;
    const int lr = lane & 15, lkq = lane >> 4;
    const int s7 = lr & 7;

    f32x4 acc[2][4] = {};

    const float* a_src = pf + (size_t)(m0 + sr) * 512 + sk;
    const float* b_src[2];
    int wbB0[2], wbB1[2];
#pragma unroll
    for (int pass = 0; pass < 2; ++pass) {
        int c = c0 + pass * 64 + sr;
        int d = c & 511;
        int koff = (c >> 9) * 512;
        b_src[pass] = W1 + (size_t)d * 1024 + koff + sk;
        int rb = pass * 64 + sr, s = rb & 7;
        wbB0[pass] = rb * 128 + (((g0    ) ^ s) << 4);
        wbB1[pass] = rb * 128 + (((g0 + 1) ^ s) << 4);
    }
    const int sA = sr & 7;
    const int wbA0 = sr * 128 + (((g0    ) ^ sA) << 4);
    const int wbA1 = sr * 128 + (((g0 + 1) ^ sA) << 4);

    for (int kt = 0; kt < 512; kt += 64) {
        // A tile: pf rows -> bf16 (swizzled write)
        {
            const float* gp = a_src + kt;
            f32x4 x0 = ((const f32x4*)gp)[0];
            f32x4 x1 = ((const f32x4*)gp)[1];
            f32x4 x2 = ((const f32x4*)gp)[2];
            f32x4 x3 = ((const f32x4*)gp)[3];
            u32x4 P0, P1;
            P0[0] = cvt2_bf16(x0[0], x0[1]); P0[1] = cvt2_bf16(x0[2], x0[3]);
            P0[2] = cvt2_bf16(x1[0], x1[1]); P0[3] = cvt2_bf16(x1[2], x1[3]);
            P1[0] = cvt2_bf16(x2[0], x2[1]); P1[1] = cvt2_bf16(x2[2], x2[3]);
            P1[2] = cvt2_bf16(x3[0], x3[1]); P1[3] = cvt2_bf16(x3[2], x3[3]);
            *(u32x4*)((char*)&As[0][0] + wbA0) = P0;
            *(u32x4*)((char*)&As[0][0] + wbA1) = P1;
        }
        // B tile: W1 columns (as B^T rows) -> bf16 (swizzled write)
#pragma unroll
        for (int pass = 0; pass < 2; ++pass) {
            const float* gp = b_src[pass] + kt;
            f32x4 x0 = ((const f32x4*)gp)[0];
            f32x4 x1 = ((const f32x4*)gp)[1];
            f32x4 x2 = ((const f32x4*)gp)[2];
            f32x4 x3 = ((const f32x4*)gp)[3];
            u32x4 P0, P1;
            P0[0] = cvt2_bf16(x0[0], x0[1]); P0[1] = cvt2_bf16(x0[2], x0[3]);
            P0[2] = cvt2_bf16(x1[0], x1[1]); P0[3] = cvt2_bf16(x1[2], x1[3]);
            P1[0] = cvt2_bf16(x2[0], x2[1]); P1[1] = cvt2_bf16(x2[2], x2[3]);
            P1[2] = cvt2_bf16(x3[0], x3[1]); P1[3] = cvt2_bf16(x3[2], x3[3]);
            *(u32x4*)((char*)&Bs[0][0] + wbB0[pass]) = P0;
            *(u32x4*)((char*)&Bs[0][0] + wbB1[pass]) = P1;
        }
        __syncthreads();
#pragma unroll
        for (int kk = 0; kk < 2; ++kk) {
            const int co = (((kk << 2) + lkq) ^ s7) << 3;   // ushort offset
            bf16x8 af[2], bfr[4];
#pragma unroll
            for (int m = 0; m < 2; ++m)
                af[m] = *(const bf16x8*)(&As[0][0] + (wr * 32 + m * 16 + lr) * 64 + co);
#pragma unroll
            for (int n = 0; n < 4; ++n)
                bfr[n] = *(const bf16x8*)(&Bs[0][0] + (wc * 64 + n * 16 + lr) * 64 + co);
#pragma unroll
            for (int m = 0; m < 2; ++m)
#pragma unroll
                for (int n = 0; n < 4; ++n)
                    acc[m][n] = __builtin_amdgcn_mfma_f32_16x16x32_bf16(
                        af[m], bfr[n], acc[m][n], 0, 0, 0);
        }
        __syncthreads();
    }

    const int cr = lane >> 4;
    const int cc = lane & 15;
#pragma unroll
    for (int m = 0; m < 2; ++m) {
#pragma unroll
        for (int n = 0; n < 4; ++n) {
            int c = c0 + wc * 64 + n * 16 + cc;
            float bias = (c < 512) ? b1[c] : 0.0f;
            int rowb = m0 + wr * 32 + m * 16 + cr * 4;
#pragma unroll
            for (int r_ = 0; r_ < 4; ++r_)
                UV[(size_t)(rowb + r_) * 1024 + c] = acc[m][n][r_] + bias;
        }
    }
}

// ---------------------------------------------------------------------------
// Kernel 3: out[m, d] = relu(U[row_i(m)] + V[row_j(m)]) @ W2^T + b2
// M=63488, N=512, K=512. Tile 128x128, BK=64, 256 thr = 4 waves 2x2.
// Double-buffered A and B (64 KB LDS), ONE barrier per K-step:
//   [barrier] -> issue UV loads(n+1) -> issue B-stage(n+1) -> MFMA(n)
//             -> relu/cvt/ds_write A(n+1)
// LDS XOR-swizzle (phys_g = g ^ (row&7)); B swizzled via per-lane global src.
// ---------------------------------------------------------------------------
__global__ __launch_bounds__(256) void fused_gemm(const float* __restrict__ UV,
                                                  const unsigned short* __restrict__ W2b,
                                                  const float* __restrict__ b2,
                                                  float* __restrict__ out) {
    __shared__ unsigned short As[2][128][64];
    __shared__ unsigned short Bs[2][128][64];

    const int t = threadIdx.x;
    const int bx = blockIdx.x;
    const int c0 = (bx & 3) << 7;     // 4 col tiles
    const int m0 = (bx >> 2) << 7;    // 496 row tiles

    const int sr = t >> 2;            // 0..63
    const int skf = (t & 3) << 4;     // float index within BK
    const int g0 = (t & 3) << 1;      // first granule of this thread's 32B

    const int wave = t >> 6, lane = t & 63;
    const int wr = wave >> 1, wc = wave & 1;
    const int lr = lane & 15, lkq = lane >> 4;
    const int s7 = lr & 7;

    // Per-thread A-row decode (K-invariant): m -> (b, i, j); swizzled write offsets
    const float* uptr[2];
    const float* vptr[2];
    int wb0[2], wb1[2];
#pragma unroll
    for (int pass = 0; pass < 2; ++pass) {
        int m = m0 + pass * 64 + sr;
        int b = m / 992;
        int p = m - b * 992;
        int i = p / 31;
        int r = p - i * 31;
        int j = r + (r >= i ? 1 : 0);
        uptr[pass] = UV + (size_t)(b * 32 + i) * 1024 + skf;
        vptr[pass] = UV + (size_t)(b * 32 + j) * 1024 + 512 + skf;
        int rowa = pass * 64 + sr, s = rowa & 7;
        wb0[pass] = rowa * 128 + (((g0    ) ^ s) << 4);
        wb1[pass] = rowa * 128 + (((g0 + 1) ^ s) << 4);
    }

    // B-stage: per-lane inverse-swizzled global source, linear LDS dest
    const int lgB = (t & 7) ^ ((t >> 3) & 7);
    const unsigned short* bsrc[4];
#pragma unroll
    for (int q = 0; q < 4; ++q)
        bsrc[q] = W2b + (size_t)(c0 + q * 32 + (t >> 3)) * 512 + lgB * 8;

    f32x4 acc[4][4] = {};

    // ---- prologue: stage B(0) and build A(0) into buffer 0
    {
#pragma unroll
        for (int q = 0; q < 4; ++q)
            async_lds16(bsrc[q], (char*)&Bs[0][0][0] + q * 4096 + wave * 1024);
#pragma unroll
        for (int pass = 0; pass < 2; ++pass) {
            const float* up = uptr[pass];
            const float* vp = vptr[pass];
            f32x4 u0 = ((const f32x4*)up)[0], u1 = ((const f32x4*)up)[1];
            f32x4 u2 = ((const f32x4*)up)[2], u3 = ((const f32x4*)up)[3];
            f32x4 v0 = ((const f32x4*)vp)[0], v1 = ((const f32x4*)vp)[1];
            f32x4 v2 = ((const f32x4*)vp)[2], v3 = ((const f32x4*)vp)[3];
            f32x4 h0, h1, h2, h3;
#pragma unroll
            for (int q = 0; q < 4; ++q) {
                h0[q] = fmaxf(u0[q] + v0[q], 0.0f);
                h1[q] = fmaxf(u1[q] + v1[q], 0.0f);
                h2[q] = fmaxf(u2[q] + v2[q], 0.0f);
                h3[q] = fmaxf(u3[q] + v3[q], 0.0f);
            }
            u32x4 P0, P1;
            P0[0] = cvt2_bf16(h0[0], h0[1]); P0[1] = cvt2_bf16(h0[2], h0[3]);
            P0[2] = cvt2_bf16(h1[0], h1[1]); P0[3] = cvt2_bf16(h1[2], h1[3]);
            P1[0] = cvt2_bf16(h2[0], h2[1]); P1[1] = cvt2_bf16(h2[2], h2[3]);
            P1[2] = cvt2_bf16(h3[0], h3[1]); P1[3] = cvt2_bf16(h3[2], h3[3]);
            *(u32x4*)((char*)&As[0][0][0] + wb0[pass]) = P0;
            *(u32x4*)((char*)&As[0][0][0] + wb1[pass]) = P1;
        }
    }

#pragma unroll 1
    for (int step = 0; step < 8; ++step) {
        const int buf = step & 1;
        __syncthreads();

        // ---- issue next-tile loads first (hide under MFMA window)
        f32x4 u[2][4], v[2][4];
        if (step < 7) {
            const int kt2 = (step + 1) << 6;
#pragma unroll
            for (int pass = 0; pass < 2; ++pass) {
#pragma unroll
                for (int qq = 0; qq < 4; ++qq) {
                    u[pass][qq] = ((const f32x4*)(uptr[pass] + kt2))[qq];
                    v[pass][qq] = ((const f32x4*)(vptr[pass] + kt2))[qq];
                }
            }
#pragma unroll
            for (int q = 0; q < 4; ++q)
                async_lds16(bsrc[q] + kt2,
                            (char*)&Bs[buf ^ 1][0][0] + q * 4096 + wave * 1024);
        }

        // ---- MFMA on current buffers (swizzled reads)
        const unsigned short* asU = &As[buf][0][0];
        const unsigned short* bsU = &Bs[buf][0][0];
#pragma unroll
        for (int kk = 0; kk < 2; ++kk) {
            const int co = (((kk << 2) + lkq) ^ s7) << 3;   // ushort offset
            bf16x8 af[4], bfr[4];
#pragma unroll
            for (int m = 0; m < 4; ++m)
                af[m] = *(const bf16x8*)(asU + (wr * 64 + m * 16 + lr) * 64 + co);
#pragma unroll
            for (int n = 0; n < 4; ++n)
                bfr[n] = *(const bf16x8*)(bsU + (wc * 64 + n * 16 + lr) * 64 + co);
#pragma unroll
            for (int m = 0; m < 4; ++m)
#pragma unroll
                for (int n = 0; n < 4; ++n)
                    acc[m][n] = __builtin_amdgcn_mfma_f32_16x16x32_bf16(
                        af[m], bfr[n], acc[m][n], 0, 0, 0);
        }

        // ---- finish A(n+1): relu/cvt, swizzled ds_write into buf^1
        if (step < 7) {
            char* asW = (char*)&As[buf ^ 1][0][0];
#pragma unroll
            for (int pass = 0; pass < 2; ++pass) {
                f32x4 h0, h1, h2, h3;
#pragma unroll
                for (int q = 0; q < 4; ++q) {
                    h0[q] = fmaxf(u[pass][0][q] + v[pass][0][q], 0.0f);
                    h1[q] = fmaxf(u[pass][1][q] + v[pass][1][q], 0.0f);
                    h2[q] = fmaxf(u[pass][2][q] + v[pass][2][q], 0.0f);
                    h3[q] = fmaxf(u[pass][3][q] + v[pass][3][q], 0.0f);
                }
                u32x4 P0, P1;
                P0[0] = cvt2_bf16(h0[0], h0[1]); P0[1] = cvt2_bf16(h0[2], h0[3]);
                P0[2] = cvt2_bf16(h1[0], h1[1]); P0[3] = cvt2_bf16(h1[2], h1[3]);
                P1[0] = cvt2_bf16(h2[0], h2[1]); P1[1] = cvt2_bf16(h2[2], h2[3]);
                P1[2] = cvt2_bf16(h3[0], h3[1]); P1[3] = cvt2_bf16(h3[2], h3[3]);
                *(u32x4*)(asW + wb0[pass]) = P0;
                *(u32x4*)(asW + wb1[pass]) = P1;
            }
        }
    }

    // epilogue: C/D layout col=lane&15, row=(lane>>4)*4+reg
    const int cr = lane >> 4;
    const int cc = lane & 15;
#pragma unroll
    for (int m = 0; m < 4; ++m) {
#pragma unroll
        for (int n = 0; n < 4; ++n) {
            int col = c0 + wc * 64 + n * 16 + cc;
            float bias = b2[col];
            int rowb = m0 + wr * 64 + m * 16 + cr * 4;
#pragma unroll
            for (int r_ = 0; r_ < 4; ++r_)
                out[(size_t)(rowb + r_) * 512 + col] = acc[m][n][r_] + bias;
        }
    }
}

// ---------------------------------------------------------------------------
extern "C" void kernel_launch(void* const* d_in, const int* in_sizes, int n_in,
                              void* d_out, int out_size, void* d_ws, size_t ws_size,
                              hipStream_t stream) {
    const float* pf = (const float*)d_in[0];   // (64, 32, 512)
    const float* W1 = (const float*)d_in[1];   // (512, 1024)
    const float* b1 = (const float*)d_in[2];   // (512,)
    const float* W2 = (const float*)d_in[3];   // (512, 512)
    const float* b2 = (const float*)d_in[4];   // (512,)
    float* out = (float*)d_out;                // (64, 992, 512)

    float* UV = (float*)d_ws;                                      // 8 MB
    unsigned short* W2b = (unsigned short*)((char*)d_ws + (size_t)8 * 1024 * 1024);

    w2_to_bf16<<<dim3(256), dim3(256), 0, stream>>>(W2, W2b);
    uv_gemm<<<dim3(256), dim3(256), 0, stream>>>(pf, W1, b1, UV);
    fused_gemm<<<dim3(1984), dim3(256), 0, stream>>>(UV, W2b, b2, out);
}

// Round 4
// 91.923 us; speedup vs baseline: 1.2312x; 1.2013x over previous
//
#include <hip/hip_runtime.h>
#include <hip/hip_bf16.h>
#include <stdint.h>

// Problem: B=64, N=32, D=512, P=992 pairs, M = B*P = 63488.
// out[m,d] = relu(U[i(m)] + V[j(m)])·W2[d,:] + b2[d]
// U = pf @ W1[:,:512]^T (+b1), V = pf @ W1[:,512:]^T   (only 2048 distinct rows)

typedef __attribute__((ext_vector_type(4))) float f32x4;
typedef __attribute__((ext_vector_type(8))) short bf16x8;
typedef __attribute__((ext_vector_type(4))) unsigned int u32x4;
typedef __attribute__((ext_vector_type(2))) unsigned int u32x2;

__device__ __forceinline__ uint32_t cvt2_bf16(float a, float b) {
    __hip_bfloat162 h = __float22bfloat162_rn(make_float2(a, b));
    uint32_t u;
    __builtin_memcpy(&u, &h, 4);
    return u;
}

__device__ __forceinline__ void async_lds16(const void* g, void* l) {
    __builtin_amdgcn_global_load_lds(
        (const __attribute__((address_space(1))) void*)g,
        (__attribute__((address_space(3))) void*)l, 16, 0, 0);
}

// ---------------------------------------------------------------------------
// Kernel 1: rearrange W2 (512x512 fp32, [d][k]) -> bf16 in MFMA-fragment order.
// Slot s (16B) = [step kt (16)][frag_n (32)][lane l (64)]:
//   col = fn*16 + (l&15), k = kt*32 + (l>>4)*8.
// Per K-step the B-stage is then a single contiguous 32KB chunk.
// NEEDS 32768 threads (one 16B slot each) -> grid 128 x 256.  (R3 bug: 64)
// ---------------------------------------------------------------------------
__global__ __launch_bounds__(256) void w2_rearrange(const float* __restrict__ W2,
                                                    unsigned short* __restrict__ W2r) {
    int s = blockIdx.x * 256 + threadIdx.x;      // 0..32767
    int l = s & 63;
    int fn = (s >> 6) & 31;
    int kt = s >> 11;
    int col = fn * 16 + (l & 15);
    int k = kt * 32 + (l >> 4) * 8;
    const float* src = W2 + (size_t)col * 512 + k;
    f32x4 a = ((const f32x4*)src)[0];
    f32x4 b = ((const f32x4*)src)[1];
    u32x4 P;
    P[0] = cvt2_bf16(a[0], a[1]); P[1] = cvt2_bf16(a[2], a[3]);
    P[2] = cvt2_bf16(b[0], b[1]); P[3] = cvt2_bf16(b[2], b[3]);
    *(u32x4*)(W2r + (size_t)s * 8) = P;
}

// ---------------------------------------------------------------------------
// Kernel 2: UV = pf @ [W1a^T | W1b^T]  (fp32 out, b1 folded into U half)
// 64x128 tile, BK=64, 256 thr / 4 waves, XOR-swizzled LDS. (2.1 GF, ~7 us)
// ---------------------------------------------------------------------------
__global__ __launch_bounds__(256) void uv_gemm(const float* __restrict__ pf,
                                               const float* __restrict__ W1,
                                               const float* __restrict__ b1,
                                               float* __restrict__ UV) {
    __shared__ unsigned short As[64][64];
    __shared__ unsigned short Bs[128][64];

    const int t = threadIdx.x;
    const int m0 = (blockIdx.x >> 3) * 64;
    const int c0 = (blockIdx.x & 7) * 128;

    const int sr = t >> 2;
    const int sk = (t & 3) << 4;
    const int g0 = (t & 3) << 1;

    const int wave = t >> 6, lane = t & 63;
    const int wr = wave >> 1, wc = wave & 1;
    const int lr = lane & 15, lkq = lane >> 4;
    const int s7 = lr & 7;

    f32x4 acc[2][4] = {};

    const float* a_src = pf + (size_t)(m0 + sr) * 512 + sk;
    const float* b_src[2];
    int wbB0[2], wbB1[2];
#pragma unroll
    for (int pass = 0; pass < 2; ++pass) {
        int c = c0 + pass * 64 + sr;
        int d = c & 511;
        int koff = (c >> 9) * 512;
        b_src[pass] = W1 + (size_t)d * 1024 + koff + sk;
        int rb = pass * 64 + sr, s = rb & 7;
        wbB0[pass] = rb * 128 + (((g0    ) ^ s) << 4);
        wbB1[pass] = rb * 128 + (((g0 + 1) ^ s) << 4);
    }
    const int sA = sr & 7;
    const int wbA0 = sr * 128 + (((g0    ) ^ sA) << 4);
    const int wbA1 = sr * 128 + (((g0 + 1) ^ sA) << 4);

    for (int kt = 0; kt < 512; kt += 64) {
        {
            const float* gp = a_src + kt;
            f32x4 x0 = ((const f32x4*)gp)[0];
            f32x4 x1 = ((const f32x4*)gp)[1];
            f32x4 x2 = ((const f32x4*)gp)[2];
            f32x4 x3 = ((const f32x4*)gp)[3];
            u32x4 P0, P1;
            P0[0] = cvt2_bf16(x0[0], x0[1]); P0[1] = cvt2_bf16(x0[2], x0[3]);
            P0[2] = cvt2_bf16(x1[0], x1[1]); P0[3] = cvt2_bf16(x1[2], x1[3]);
            P1[0] = cvt2_bf16(x2[0], x2[1]); P1[1] = cvt2_bf16(x2[2], x2[3]);
            P1[2] = cvt2_bf16(x3[0], x3[1]); P1[3] = cvt2_bf16(x3[2], x3[3]);
            *(u32x4*)((char*)&As[0][0] + wbA0) = P0;
            *(u32x4*)((char*)&As[0][0] + wbA1) = P1;
        }
#pragma unroll
        for (int pass = 0; pass < 2; ++pass) {
            const float* gp = b_src[pass] + kt;
            f32x4 x0 = ((const f32x4*)gp)[0];
            f32x4 x1 = ((const f32x4*)gp)[1];
            f32x4 x2 = ((const f32x4*)gp)[2];
            f32x4 x3 = ((const f32x4*)gp)[3];
            u32x4 P0, P1;
            P0[0] = cvt2_bf16(x0[0], x0[1]); P0[1] = cvt2_bf16(x0[2], x0[3]);
            P0[2] = cvt2_bf16(x1[0], x1[1]); P0[3] = cvt2_bf16(x1[2], x1[3]);
            P1[0] = cvt2_bf16(x2[0], x2[1]); P1[1] = cvt2_bf16(x2[2], x2[3]);
            P1[2] = cvt2_bf16(x3[0], x3[1]); P1[3] = cvt2_bf16(x3[2], x3[3]);
            *(u32x4*)((char*)&Bs[0][0] + wbB0[pass]) = P0;
            *(u32x4*)((char*)&Bs[0][0] + wbB1[pass]) = P1;
        }
        __syncthreads();
#pragma unroll
        for (int kk = 0; kk < 2; ++kk) {
            const int co = (((kk << 2) + lkq) ^ s7) << 3;
            bf16x8 af[2], bfr[4];
#pragma unroll
            for (int m = 0; m < 2; ++m)
                af[m] = *(const bf16x8*)(&As[0][0] + (wr * 32 + m * 16 + lr) * 64 + co);
#pragma unroll
            for (int n = 0; n < 4; ++n)
                bfr[n] = *(const bf16x8*)(&Bs[0][0] + (wc * 64 + n * 16 + lr) * 64 + co);
#pragma unroll
            for (int m = 0; m < 2; ++m)
#pragma unroll
                for (int n = 0; n < 4; ++n)
                    acc[m][n] = __builtin_amdgcn_mfma_f32_16x16x32_bf16(
                        af[m], bfr[n], acc[m][n], 0, 0, 0);
        }
        __syncthreads();
    }

    const int cr = lane >> 4;
    const int cc = lane & 15;
#pragma unroll
    for (int m = 0; m < 2; ++m) {
#pragma unroll
        for (int n = 0; n < 4; ++n) {
            int c = c0 + wc * 64 + n * 16 + cc;
            float bias = (c < 512) ? b1[c] : 0.0f;
            int rowb = m0 + wr * 32 + m * 16 + cr * 4;
#pragma unroll
            for (int r_ = 0; r_ < 4; ++r_)
                UV[(size_t)(rowb + r_) * 1024 + c] = acc[m][n][r_] + bias;
        }
    }
}

// ---------------------------------------------------------------------------
// Kernel 3: out = relu(U[i]+V[j]) @ W2^T + b2.
// BM=128, BN=512 (full width -> no col-tile UV duplication), BK=32, 16 steps.
// 512 threads = 8 waves (2M x 4N), wave tile 64x128, acc 8x4x4 = 128 regs.
// LDS fragment-major (conflict-free by construction), A+B double-buffered,
// one barrier per step. XCD-chunked m-tiles keep UV slice L2-resident.
// ---------------------------------------------------------------------------
__global__ __launch_bounds__(512, 2) void fused_gemm(const float* __restrict__ UV,
                                                     const unsigned short* __restrict__ W2r,
                                                     const float* __restrict__ b2,
                                                     float* __restrict__ out) {
    // fragment-major: frag*1024 + lane*16 bytes
    __shared__ unsigned char As[2][8192];    // 8 m-frags
    __shared__ unsigned char Bs[2][32768];   // 32 n-frags

    const int t = threadIdx.x;
    const int bx = blockIdx.x;
    const int mt = (bx & 7) * 62 + (bx >> 3);   // XCD-chunked, bijective (496=8*62)
    const int m0 = mt << 7;

    const int wave = t >> 6, lane = t & 63;
    const int wr = wave >> 2;        // 0..1  (M group)
    const int wc = wave & 3;         // 0..3  (N group of 128 cols)

    // ---- A-build mapping: thread -> (pair row, k-slice)
    const int arow = t >> 2;         // 0..127
    const int ks = t & 3;            // k-slice (8 floats)
    const float* uptr;
    const float* vptr;
    {
        int m = m0 + arow;
        int b = m / 992;
        int p = m - b * 992;
        int i = p / 31;
        int r = p - i * 31;
        int j = r + (r >= i ? 1 : 0);
        uptr = UV + (size_t)(b * 32 + i) * 1024 + ks * 8;
        vptr = UV + (size_t)(b * 32 + j) * 1024 + 512 + ks * 8;
    }
    const int awoff = ((arow >> 4) * 64 + (arow & 15) + ks * 16) * 16;  // byte

    f32x4 acc[8][4] = {};   // 8 N-frags x 4 M-frags

    // ---- prologue: stage B(0), build A(0)
    {
        const char* gs = (const char*)W2r + t * 16;
#pragma unroll
        for (int q = 0; q < 4; ++q)
            async_lds16(gs + q * 8192, &Bs[0][0] + q * 8192 + wave * 1024);

        f32x4 u0 = ((const f32x4*)uptr)[0], u1 = ((const f32x4*)uptr)[1];
        f32x4 v0 = ((const f32x4*)vptr)[0], v1 = ((const f32x4*)vptr)[1];
        f32x4 h0, h1;
#pragma unroll
        for (int q = 0; q < 4; ++q) {
            h0[q] = fmaxf(u0[q] + v0[q], 0.0f);
            h1[q] = fmaxf(u1[q] + v1[q], 0.0f);
        }
        u32x4 P;
        P[0] = cvt2_bf16(h0[0], h0[1]); P[1] = cvt2_bf16(h0[2], h0[3]);
        P[2] = cvt2_bf16(h1[0], h1[1]); P[3] = cvt2_bf16(h1[2], h1[3]);
        *(u32x4*)(&As[0][0] + awoff) = P;
    }

#pragma unroll 1
    for (int step = 0; step < 16; ++step) {
        const int buf = step & 1;
        __syncthreads();

        f32x4 u0, u1, v0, v1;
        if (step < 15) {
            // stage B(step+1): contiguous 32KB chunk, lane-linear DMA
            const char* gs = (const char*)W2r + (step + 1) * 32768 + t * 16;
#pragma unroll
            for (int q = 0; q < 4; ++q)
                async_lds16(gs + q * 8192, &Bs[buf ^ 1][0] + q * 8192 + wave * 1024);
            // load UV(step+1)
            const float* up = uptr + (step + 1) * 32;
            const float* vp = vptr + (step + 1) * 32;
            u0 = ((const f32x4*)up)[0]; u1 = ((const f32x4*)up)[1];
            v0 = ((const f32x4*)vp)[0]; v1 = ((const f32x4*)vp)[1];
        }

        // ---- MFMA on current buffers (fragment-major, lane-linear reads)
        {
            const unsigned char* aB = &As[buf][0];
            const unsigned char* bB = &Bs[buf][0];
            bf16x8 af[4], bfr[8];
#pragma unroll
            for (int m = 0; m < 4; ++m)
                af[m] = *(const bf16x8*)(aB + (wr * 4 + m) * 1024 + lane * 16);
#pragma unroll
            for (int n = 0; n < 8; ++n)
                bfr[n] = *(const bf16x8*)(bB + (wc * 8 + n) * 1024 + lane * 16);
#pragma unroll
            for (int n = 0; n < 8; ++n)
#pragma unroll
                for (int m = 0; m < 4; ++m)
                    acc[n][m] = __builtin_amdgcn_mfma_f32_16x16x32_bf16(
                        af[m], bfr[n], acc[n][m], 0, 0, 0);
        }

        // ---- finish A(step+1): relu/cvt -> frag-major ds_write
        if (step < 15) {
            f32x4 h0, h1;
#pragma unroll
            for (int q = 0; q < 4; ++q) {
                h0[q] = fmaxf(u0[q] + v0[q], 0.0f);
                h1[q] = fmaxf(u1[q] + v1[q], 0.0f);
            }
            u32x4 P;
            P[0] = cvt2_bf16(h0[0], h0[1]); P[1] = cvt2_bf16(h0[2], h0[3]);
            P[2] = cvt2_bf16(h1[0], h1[1]); P[3] = cvt2_bf16(h1[2], h1[3]);
            *(u32x4*)(&As[buf ^ 1][0] + awoff) = P;
        }
    }

    // ---- epilogue: C/D layout col=lane&15, row=(lane>>4)*4+reg
    const int cr = lane >> 4;
    const int cc = lane & 15;
#pragma unroll
    for (int n = 0; n < 8; ++n) {
        int col = wc * 128 + n * 16 + cc;
        float bias = b2[col];
#pragma unroll
        for (int m = 0; m < 4; ++m) {
            int rowb = m0 + wr * 64 + m * 16 + cr * 4;
#pragma unroll
            for (int r_ = 0; r_ < 4; ++r_)
                out[(size_t)(rowb + r_) * 512 + col] = acc[n][m][r_] + bias;
        }
    }
}

// ---------------------------------------------------------------------------
extern "C" void kernel_launch(void* const* d_in, const int* in_sizes, int n_in,
                              void* d_out, int out_size, void* d_ws, size_t ws_size,
                              hipStream_t stream) {
    const float* pf = (const float*)d_in[0];   // (64, 32, 512)
    const float* W1 = (const float*)d_in[1];   // (512, 1024)
    const float* b1 = (const float*)d_in[2];   // (512,)
    const float* W2 = (const float*)d_in[3];   // (512, 512)
    const float* b2 = (const float*)d_in[4];   // (512,)
    float* out = (float*)d_out;                // (64, 992, 512)

    float* UV = (float*)d_ws;                                       // 8 MB
    unsigned short* W2r = (unsigned short*)((char*)d_ws + (size_t)8 * 1024 * 1024); // 512 KB

    w2_rearrange<<<dim3(128), dim3(256), 0, stream>>>(W2, W2r);     // 32768 slots
    uv_gemm<<<dim3(256), dim3(256), 0, stream>>>(pf, W1, b1, UV);
    fused_gemm<<<dim3(496), dim3(512), 0, stream>>>(UV, W2r, b2, out);
}

// Round 5
// 85.209 us; speedup vs baseline: 1.3282x; 1.0788x over previous
//
#include <hip/hip_runtime.h>
#include <hip/hip_bf16.h>
#include <stdint.h>

// Problem: B=64, N=32, D=512, P=992 pairs, M = B*P = 63488.
// out[m,d] = relu(U[i(m)] + V[j(m)])·W2[d,:] + b2[d]
// U = pf @ W1[:,:512]^T (+b1), V = pf @ W1[:,512:]^T   (only 2048 distinct rows)

typedef __attribute__((ext_vector_type(4))) float f32x4;
typedef __attribute__((ext_vector_type(8))) short bf16x8;
typedef __attribute__((ext_vector_type(4))) unsigned int u32x4;
typedef __attribute__((ext_vector_type(2))) unsigned int u32x2;

__device__ __forceinline__ uint32_t cvt2_bf16(float a, float b) {
    __hip_bfloat162 h = __float22bfloat162_rn(make_float2(a, b));
    uint32_t u;
    __builtin_memcpy(&u, &h, 4);
    return u;
}

__device__ __forceinline__ void async_lds16(const void* g, void* l) {
    __builtin_amdgcn_global_load_lds(
        (const __attribute__((address_space(1))) void*)g,
        (__attribute__((address_space(3))) void*)l, 16, 0, 0);
}

// ---------------------------------------------------------------------------
// Kernel 1 (merged): blocks 0..255 -> uv_gemm tile; blocks 256..383 ->
// W2 rearrange into MFMA-fragment order (32768 16B slots).
// ---------------------------------------------------------------------------
__global__ __launch_bounds__(256) void prep(const float* __restrict__ pf,
                                            const float* __restrict__ W1,
                                            const float* __restrict__ b1,
                                            const float* __restrict__ W2,
                                            float* __restrict__ UV,
                                            unsigned short* __restrict__ W2r) {
    __shared__ unsigned short As[64][64];
    __shared__ unsigned short Bs[128][64];

    const int t = threadIdx.x;
    const int bxg = blockIdx.x;

    if (bxg >= 256) {
        // ---- W2 rearrange: slot s = [kt(16)][fn(32)][l(64)]
        int s = (bxg - 256) * 256 + t;           // 0..32767
        int l = s & 63;
        int fn = (s >> 6) & 31;
        int kt = s >> 11;
        int col = fn * 16 + (l & 15);
        int k = kt * 32 + (l >> 4) * 8;
        const float* src = W2 + (size_t)col * 512 + k;
        f32x4 a = ((const f32x4*)src)[0];
        f32x4 b = ((const f32x4*)src)[1];
        u32x4 P;
        P[0] = cvt2_bf16(a[0], a[1]); P[1] = cvt2_bf16(a[2], a[3]);
        P[2] = cvt2_bf16(b[0], b[1]); P[3] = cvt2_bf16(b[2], b[3]);
        *(u32x4*)(W2r + (size_t)s * 8) = P;
        return;
    }

    // ---- uv_gemm: 64x128 tile, BK=64, 4 waves, XOR-swizzled LDS
    const int m0 = (bxg >> 3) * 64;
    const int c0 = (bxg & 7) * 128;

    const int sr = t >> 2;
    const int sk = (t & 3) << 4;
    const int g0 = (t & 3) << 1;

    const int wave = t >> 6, lane = t & 63;
    const int wr = wave >> 1, wc = wave & 1;
    const int lr = lane & 15, lkq = lane >> 4;
    const int s7 = lr & 7;

    f32x4 acc[2][4] = {};

    const float* a_src = pf + (size_t)(m0 + sr) * 512 + sk;
    const float* b_src[2];
    int wbB0[2], wbB1[2];
#pragma unroll
    for (int pass = 0; pass < 2; ++pass) {
        int c = c0 + pass * 64 + sr;
        int d = c & 511;
        int koff = (c >> 9) * 512;
        b_src[pass] = W1 + (size_t)d * 1024 + koff + sk;
        int rb = pass * 64 + sr, s = rb & 7;
        wbB0[pass] = rb * 128 + (((g0    ) ^ s) << 4);
        wbB1[pass] = rb * 128 + (((g0 + 1) ^ s) << 4);
    }
    const int sA = sr & 7;
    const int wbA0 = sr * 128 + (((g0    ) ^ sA) << 4);
    const int wbA1 = sr * 128 + (((g0 + 1) ^ sA) << 4);

    for (int kt = 0; kt < 512; kt += 64) {
        {
            const float* gp = a_src + kt;
            f32x4 x0 = ((const f32x4*)gp)[0];
            f32x4 x1 = ((const f32x4*)gp)[1];
            f32x4 x2 = ((const f32x4*)gp)[2];
            f32x4 x3 = ((const f32x4*)gp)[3];
            u32x4 P0, P1;
            P0[0] = cvt2_bf16(x0[0], x0[1]); P0[1] = cvt2_bf16(x0[2], x0[3]);
            P0[2] = cvt2_bf16(x1[0], x1[1]); P0[3] = cvt2_bf16(x1[2], x1[3]);
            P1[0] = cvt2_bf16(x2[0], x2[1]); P1[1] = cvt2_bf16(x2[2], x2[3]);
            P1[2] = cvt2_bf16(x3[0], x3[1]); P1[3] = cvt2_bf16(x3[2], x3[3]);
            *(u32x4*)((char*)&As[0][0] + wbA0) = P0;
            *(u32x4*)((char*)&As[0][0] + wbA1) = P1;
        }
#pragma unroll
        for (int pass = 0; pass < 2; ++pass) {
            const float* gp = b_src[pass] + kt;
            f32x4 x0 = ((const f32x4*)gp)[0];
            f32x4 x1 = ((const f32x4*)gp)[1];
            f32x4 x2 = ((const f32x4*)gp)[2];
            f32x4 x3 = ((const f32x4*)gp)[3];
            u32x4 P0, P1;
            P0[0] = cvt2_bf16(x0[0], x0[1]); P0[1] = cvt2_bf16(x0[2], x0[3]);
            P0[2] = cvt2_bf16(x1[0], x1[1]); P0[3] = cvt2_bf16(x1[2], x1[3]);
            P1[0] = cvt2_bf16(x2[0], x2[1]); P1[1] = cvt2_bf16(x2[2], x2[3]);
            P1[2] = cvt2_bf16(x3[0], x3[1]); P1[3] = cvt2_bf16(x3[2], x3[3]);
            *(u32x4*)((char*)&Bs[0][0] + wbB0[pass]) = P0;
            *(u32x4*)((char*)&Bs[0][0] + wbB1[pass]) = P1;
        }
        __syncthreads();
#pragma unroll
        for (int kk = 0; kk < 2; ++kk) {
            const int co = (((kk << 2) + lkq) ^ s7) << 3;
            bf16x8 af[2], bfr[4];
#pragma unroll
            for (int m = 0; m < 2; ++m)
                af[m] = *(const bf16x8*)(&As[0][0] + (wr * 32 + m * 16 + lr) * 64 + co);
#pragma unroll
            for (int n = 0; n < 4; ++n)
                bfr[n] = *(const bf16x8*)(&Bs[0][0] + (wc * 64 + n * 16 + lr) * 64 + co);
#pragma unroll
            for (int m = 0; m < 2; ++m)
#pragma unroll
                for (int n = 0; n < 4; ++n)
                    acc[m][n] = __builtin_amdgcn_mfma_f32_16x16x32_bf16(
                        af[m], bfr[n], acc[m][n], 0, 0, 0);
        }
        __syncthreads();
    }

    const int cr = lane >> 4;
    const int cc = lane & 15;
#pragma unroll
    for (int m = 0; m < 2; ++m) {
#pragma unroll
        for (int n = 0; n < 4; ++n) {
            int c = c0 + wc * 64 + n * 16 + cc;
            float bias = (c < 512) ? b1[c] : 0.0f;
            int rowb = m0 + wr * 32 + m * 16 + cr * 4;
#pragma unroll
            for (int r_ = 0; r_ < 4; ++r_)
                UV[(size_t)(rowb + r_) * 1024 + c] = acc[m][n][r_] + bias;
        }
    }
}

// ---------------------------------------------------------------------------
// Kernel 2: out = relu(U[i]+V[j]) @ W2^T + b2.
// BM=128, BN=512, BK=32, 16 steps. 512 thr = 8 waves (2M x 4N).
// T4 counted-wait pipeline: ONE raw s_barrier per step; the only vmcnt(0)
// lands on a DMA issued a full MFMA-phase earlier. Next-step DMA + UV loads
// are issued AFTER the barrier and stay in flight through the MFMA cluster.
// T5: setprio(1) around MFMA. LDS fragment-major, A+B double-buffered.
// ---------------------------------------------------------------------------
__global__ __launch_bounds__(512, 2) void fused_gemm(const float* __restrict__ UV,
                                                     const unsigned short* __restrict__ W2r,
                                                     const float* __restrict__ b2,
                                                     float* __restrict__ out) {
    // fragment-major: frag*1024 + lane*16 bytes
    __shared__ unsigned char As[2][8192];    // 8 m-frags
    __shared__ unsigned char Bs[2][32768];   // 32 n-frags

    const int t = threadIdx.x;
    const int bx = blockIdx.x;
    const int mt = (bx & 7) * 62 + (bx >> 3);   // XCD-chunked, bijective (496=8*62)
    const int m0 = mt << 7;

    const int wave = t >> 6, lane = t & 63;
    const int wr = wave >> 2;        // 0..1  (M group)
    const int wc = wave & 3;         // 0..3  (N group of 128 cols)

    // ---- A-build mapping: thread -> (pair row, k-slice)
    const int arow = t >> 2;         // 0..127
    const int ks = t & 3;            // k-slice (8 floats)
    const float* uptr;
    const float* vptr;
    {
        int m = m0 + arow;
        int b = m / 992;
        int p = m - b * 992;
        int i = p / 31;
        int r = p - i * 31;
        int j = r + (r >= i ? 1 : 0);
        uptr = UV + (size_t)(b * 32 + i) * 1024 + ks * 8;
        vptr = UV + (size_t)(b * 32 + j) * 1024 + 512 + ks * 8;
    }
    const int awoff = ((arow >> 4) * 64 + (arow & 15) + ks * 16) * 16;  // byte

    f32x4 acc[8][4] = {};   // 8 N-frags x 4 M-frags

    // ---- prologue: UV(0) loads, DMA B(0), build A(0) into buffer 0
    {
        f32x4 u0 = ((const f32x4*)uptr)[0], u1 = ((const f32x4*)uptr)[1];
        f32x4 v0 = ((const f32x4*)vptr)[0], v1 = ((const f32x4*)vptr)[1];

        const char* gs = (const char*)W2r + t * 16;
#pragma unroll
        for (int q = 0; q < 4; ++q)
            async_lds16(gs + q * 8192, &Bs[0][0] + q * 8192 + wave * 1024);

        f32x4 h0, h1;
#pragma unroll
        for (int q = 0; q < 4; ++q) {
            h0[q] = fmaxf(u0[q] + v0[q], 0.0f);
            h1[q] = fmaxf(u1[q] + v1[q], 0.0f);
        }
        u32x4 P;
        P[0] = cvt2_bf16(h0[0], h0[1]); P[1] = cvt2_bf16(h0[2], h0[3]);
        P[2] = cvt2_bf16(h1[0], h1[1]); P[3] = cvt2_bf16(h1[2], h1[3]);
        *(u32x4*)(&As[0][0] + awoff) = P;
        asm volatile("s_waitcnt lgkmcnt(0)" ::: "memory");
    }

#pragma unroll 1
    for (int step = 0; step < 16; ++step) {
        const int buf = step & 1;

        // Only drain: DMA B(step), issued one full phase ago. A(step) writes
        // were lgkm-drained before the barrier; barrier makes both visible
        // and proves all waves finished reading buf^1.
        asm volatile("s_waitcnt vmcnt(0)" ::: "memory");
        __builtin_amdgcn_s_barrier();
        asm volatile("" ::: "memory");

        // ---- issue next-step loads AFTER the barrier; they outlive it
        f32x4 u0, u1, v0, v1;
        if (step < 15) {
            const float* up = uptr + (step + 1) * 32;
            const float* vp = vptr + (step + 1) * 32;
            u0 = ((const f32x4*)up)[0]; u1 = ((const f32x4*)up)[1];
            v0 = ((const f32x4*)vp)[0]; v1 = ((const f32x4*)vp)[1];
            const char* gs = (const char*)W2r + (step + 1) * 32768 + t * 16;
#pragma unroll
            for (int q = 0; q < 4; ++q)
                async_lds16(gs + q * 8192, &Bs[buf ^ 1][0] + q * 8192 + wave * 1024);
        }
        asm volatile("" ::: "memory");   // pin issue order before ds_reads

        // ---- MFMA on current buffers (fragment-major, lane-linear reads)
        {
            const unsigned char* aB = &As[buf][0];
            const unsigned char* bB = &Bs[buf][0];
            bf16x8 af[4], bfr[8];
#pragma unroll
            for (int m = 0; m < 4; ++m)
                af[m] = *(const bf16x8*)(aB + (wr * 4 + m) * 1024 + lane * 16);
#pragma unroll
            for (int n = 0; n < 8; ++n)
                bfr[n] = *(const bf16x8*)(bB + (wc * 8 + n) * 1024 + lane * 16);
            __builtin_amdgcn_s_setprio(1);
#pragma unroll
            for (int n = 0; n < 8; ++n)
#pragma unroll
                for (int m = 0; m < 4; ++m)
                    acc[n][m] = __builtin_amdgcn_mfma_f32_16x16x32_bf16(
                        af[m], bfr[n], acc[n][m], 0, 0, 0);
            __builtin_amdgcn_s_setprio(0);
        }

        // ---- finish A(step+1): relu/cvt -> frag-major ds_write into buf^1
        if (step < 15) {
            f32x4 h0, h1;
#pragma unroll
            for (int q = 0; q < 4; ++q) {
                h0[q] = fmaxf(u0[q] + v0[q], 0.0f);
                h1[q] = fmaxf(u1[q] + v1[q], 0.0f);
            }
            u32x4 P;
            P[0] = cvt2_bf16(h0[0], h0[1]); P[1] = cvt2_bf16(h0[2], h0[3]);
            P[2] = cvt2_bf16(h1[0], h1[1]); P[3] = cvt2_bf16(h1[2], h1[3]);
            *(u32x4*)(&As[buf ^ 1][0] + awoff) = P;
        }
        // drain own ds_writes (and long-done ds_reads) before next barrier
        asm volatile("s_waitcnt lgkmcnt(0)" ::: "memory");
    }

    // ---- epilogue: C/D layout col=lane&15, row=(lane>>4)*4+reg
    const int cr = lane >> 4;
    const int cc = lane & 15;
#pragma unroll
    for (int n = 0; n < 8; ++n) {
        int col = wc * 128 + n * 16 + cc;
        float bias = b2[col];
#pragma unroll
        for (int m = 0; m < 4; ++m) {
            int rowb = m0 + wr * 64 + m * 16 + cr * 4;
#pragma unroll
            for (int r_ = 0; r_ < 4; ++r_)
                out[(size_t)(rowb + r_) * 512 + col] = acc[n][m][r_] + bias;
        }
    }
}

// ---------------------------------------------------------------------------
extern "C" void kernel_launch(void* const* d_in, const int* in_sizes, int n_in,
                              void* d_out, int out_size, void* d_ws, size_t ws_size,
                              hipStream_t stream) {
    const float* pf = (const float*)d_in[0];   // (64, 32, 512)
    const float* W1 = (const float*)d_in[1];   // (512, 1024)
    const float* b1 = (const float*)d_in[2];   // (512,)
    const float* W2 = (const float*)d_in[3];   // (512, 512)
    const float* b2 = (const float*)d_in[4];   // (512,)
    float* out = (float*)d_out;                // (64, 992, 512)

    float* UV = (float*)d_ws;                                       // 8 MB
    unsigned short* W2r = (unsigned short*)((char*)d_ws + (size_t)8 * 1024 * 1024); // 512 KB

    prep<<<dim3(384), dim3(256), 0, stream>>>(pf, W1, b1, W2, UV, W2r);
    fused_gemm<<<dim3(496), dim3(512), 0, stream>>>(UV, W2r, b2, out);
}

// Round 6
// 83.849 us; speedup vs baseline: 1.3498x; 1.0162x over previous
//
#include <hip/hip_runtime.h>
#include <hip/hip_bf16.h>
#include <stdint.h>

// Problem: B=64, N=32, D=512, P=992 pairs, M = B*P = 63488.
// out[m,d] = relu(U[i(m)] + V[j(m)])·W2[d,:] + b2[d]
// U = pf @ W1[:,:512]^T (+b1), V = pf @ W1[:,512:]^T   (only 2048 distinct rows)

typedef __attribute__((ext_vector_type(4))) float f32x4;
typedef __attribute__((ext_vector_type(8))) short bf16x8;
typedef __attribute__((ext_vector_type(4))) unsigned int u32x4;
typedef __attribute__((ext_vector_type(2))) unsigned int u32x2;

__device__ __forceinline__ uint32_t cvt2_bf16(float a, float b) {
    __hip_bfloat162 h = __float22bfloat162_rn(make_float2(a, b));
    uint32_t u;
    __builtin_memcpy(&u, &h, 4);
    return u;
}

__device__ __forceinline__ void async_lds16(const void* g, void* l) {
    __builtin_amdgcn_global_load_lds(
        (const __attribute__((address_space(1))) void*)g,
        (__attribute__((address_space(3))) void*)l, 16, 0, 0);
}

// ---------------------------------------------------------------------------
// Kernel 1 (merged): blocks 0..255 -> uv_gemm tile; blocks 256..383 ->
// W2 rearrange into MFMA-fragment order (32768 16B slots).
// ---------------------------------------------------------------------------
__global__ __launch_bounds__(256) void prep(const float* __restrict__ pf,
                                            const float* __restrict__ W1,
                                            const float* __restrict__ b1,
                                            const float* __restrict__ W2,
                                            float* __restrict__ UV,
                                            unsigned short* __restrict__ W2r) {
    __shared__ unsigned short As[64][64];
    __shared__ unsigned short Bs[128][64];

    const int t = threadIdx.x;
    const int bxg = blockIdx.x;

    if (bxg >= 256) {
        // ---- W2 rearrange: slot s = [kt(16)][fn(32)][l(64)]
        int s = (bxg - 256) * 256 + t;           // 0..32767
        int l = s & 63;
        int fn = (s >> 6) & 31;
        int kt = s >> 11;
        int col = fn * 16 + (l & 15);
        int k = kt * 32 + (l >> 4) * 8;
        const float* src = W2 + (size_t)col * 512 + k;
        f32x4 a = ((const f32x4*)src)[0];
        f32x4 b = ((const f32x4*)src)[1];
        u32x4 P;
        P[0] = cvt2_bf16(a[0], a[1]); P[1] = cvt2_bf16(a[2], a[3]);
        P[2] = cvt2_bf16(b[0], b[1]); P[3] = cvt2_bf16(b[2], b[3]);
        *(u32x4*)(W2r + (size_t)s * 8) = P;
        return;
    }

    // ---- uv_gemm: 64x128 tile, BK=64, 4 waves, XOR-swizzled LDS
    const int m0 = (bxg >> 3) * 64;
    const int c0 = (bxg & 7) * 128;

    const int sr = t >> 2;
    const int sk = (t & 3) << 4;
    const int g0 = (t & 3) << 1;

    const int wave = t >> 6, lane = t & 63;
    const int wr = wave >> 1, wc = wave & 1;
    const int lr = lane & 15, lkq = lane >> 4;
    const int s7 = lr & 7;

    f32x4 acc[2][4] = {};

    const float* a_src = pf + (size_t)(m0 + sr) * 512 + sk;
    const float* b_src[2];
    int wbB0[2], wbB1[2];
#pragma unroll
    for (int pass = 0; pass < 2; ++pass) {
        int c = c0 + pass * 64 + sr;
        int d = c & 511;
        int koff = (c >> 9) * 512;
        b_src[pass] = W1 + (size_t)d * 1024 + koff + sk;
        int rb = pass * 64 + sr, s = rb & 7;
        wbB0[pass] = rb * 128 + (((g0    ) ^ s) << 4);
        wbB1[pass] = rb * 128 + (((g0 + 1) ^ s) << 4);
    }
    const int sA = sr & 7;
    const int wbA0 = sr * 128 + (((g0    ) ^ sA) << 4);
    const int wbA1 = sr * 128 + (((g0 + 1) ^ sA) << 4);

    for (int kt = 0; kt < 512; kt += 64) {
        {
            const float* gp = a_src + kt;
            f32x4 x0 = ((const f32x4*)gp)[0];
            f32x4 x1 = ((const f32x4*)gp)[1];
            f32x4 x2 = ((const f32x4*)gp)[2];
            f32x4 x3 = ((const f32x4*)gp)[3];
            u32x4 P0, P1;
            P0[0] = cvt2_bf16(x0[0], x0[1]); P0[1] = cvt2_bf16(x0[2], x0[3]);
            P0[2] = cvt2_bf16(x1[0], x1[1]); P0[3] = cvt2_bf16(x1[2], x1[3]);
            P1[0] = cvt2_bf16(x2[0], x2[1]); P1[1] = cvt2_bf16(x2[2], x2[3]);
            P1[2] = cvt2_bf16(x3[0], x3[1]); P1[3] = cvt2_bf16(x3[2], x3[3]);
            *(u32x4*)((char*)&As[0][0] + wbA0) = P0;
            *(u32x4*)((char*)&As[0][0] + wbA1) = P1;
        }
#pragma unroll
        for (int pass = 0; pass < 2; ++pass) {
            const float* gp = b_src[pass] + kt;
            f32x4 x0 = ((const f32x4*)gp)[0];
            f32x4 x1 = ((const f32x4*)gp)[1];
            f32x4 x2 = ((const f32x4*)gp)[2];
            f32x4 x3 = ((const f32x4*)gp)[3];
            u32x4 P0, P1;
            P0[0] = cvt2_bf16(x0[0], x0[1]); P0[1] = cvt2_bf16(x0[2], x0[3]);
            P0[2] = cvt2_bf16(x1[0], x1[1]); P0[3] = cvt2_bf16(x1[2], x1[3]);
            P1[0] = cvt2_bf16(x2[0], x2[1]); P1[1] = cvt2_bf16(x2[2], x2[3]);
            P1[2] = cvt2_bf16(x3[0], x3[1]); P1[3] = cvt2_bf16(x3[2], x3[3]);
            *(u32x4*)((char*)&Bs[0][0] + wbB0[pass]) = P0;
            *(u32x4*)((char*)&Bs[0][0] + wbB1[pass]) = P1;
        }
        __syncthreads();
#pragma unroll
        for (int kk = 0; kk < 2; ++kk) {
            const int co = (((kk << 2) + lkq) ^ s7) << 3;
            bf16x8 af[2], bfr[4];
#pragma unroll
            for (int m = 0; m < 2; ++m)
                af[m] = *(const bf16x8*)(&As[0][0] + (wr * 32 + m * 16 + lr) * 64 + co);
#pragma unroll
            for (int n = 0; n < 4; ++n)
                bfr[n] = *(const bf16x8*)(&Bs[0][0] + (wc * 64 + n * 16 + lr) * 64 + co);
#pragma unroll
            for (int m = 0; m < 2; ++m)
#pragma unroll
                for (int n = 0; n < 4; ++n)
                    acc[m][n] = __builtin_amdgcn_mfma_f32_16x16x32_bf16(
                        af[m], bfr[n], acc[m][n], 0, 0, 0);
        }
        __syncthreads();
    }

    const int cr = lane >> 4;
    const int cc = lane & 15;
#pragma unroll
    for (int m = 0; m < 2; ++m) {
#pragma unroll
        for (int n = 0; n < 4; ++n) {
            int c = c0 + wc * 64 + n * 16 + cc;
            float bias = (c < 512) ? b1[c] : 0.0f;
            int rowb = m0 + wr * 32 + m * 16 + cr * 4;
#pragma unroll
            for (int r_ = 0; r_ < 4; ++r_)
                UV[(size_t)(rowb + r_) * 1024 + c] = acc[m][n][r_] + bias;
        }
    }
}

// ---------------------------------------------------------------------------
// Kernel 2: out = relu(U[i]+V[j]) @ W2^T + b2.
// Grid 248 (8 XCD x 31). Each block: TWO consecutive 128-row tiles, BN=512,
// BK=32, 16 steps each (g = 0..31, seg = g>>4). Tile-0 stores issued between
// the K-loops -> HBM drain overlaps tile-1 compute.
// B triple-buffered (DMA depth 2, never drained to 0: the A-build's UV
// vmcnt(4) transitively proves DMA(g+1) done before barrier g+1).
// A double-buffered. LDS 112 KB, 1 block/CU, 8 waves (2M x 4N).
// ---------------------------------------------------------------------------
__global__ __launch_bounds__(512, 2) void fused_gemm(const float* __restrict__ UV,
                                                     const unsigned short* __restrict__ W2r,
                                                     const float* __restrict__ b2,
                                                     float* __restrict__ out) {
    __shared__ unsigned char As[2][8192];     // 8 m-frags, frag-major
    __shared__ unsigned char Bs[3][32768];    // 32 n-frags, frag-major

    const int t = threadIdx.x;
    const int bx = blockIdx.x;
    const int pair = (bx & 7) * 31 + (bx >> 3);   // XCD-chunked, bijective (248=8*31)
    const int m0A = pair << 8;                    // tile0 rows [m0A, m0A+128)
    const int m0B = m0A + 128;                    // tile1 rows

    const int wave = t >> 6, lane = t & 63;
    const int wr = wave >> 2;        // 0..1  (M group)
    const int wc = wave & 3;         // 0..3  (N group of 128 cols)

    // ---- A-build mapping for both tiles: thread -> (pair row, k-slice)
    const int arow = t >> 2;         // 0..127
    const int ks = t & 3;            // k-slice (8 floats)
    const float *uptrA, *vptrA, *uptrB, *vptrB;
    {
        int m = m0A + arow;
        int b = m / 992, p = m - b * 992;
        int i = p / 31, r = p - i * 31;
        int j = r + (r >= i ? 1 : 0);
        uptrA = UV + (size_t)(b * 32 + i) * 1024 + ks * 8;
        vptrA = UV + (size_t)(b * 32 + j) * 1024 + 512 + ks * 8;
        m = m0B + arow;
        b = m / 992; p = m - b * 992;
        i = p / 31; r = p - i * 31;
        j = r + (r >= i ? 1 : 0);
        uptrB = UV + (size_t)(b * 32 + i) * 1024 + ks * 8;
        vptrB = UV + (size_t)(b * 32 + j) * 1024 + 512 + ks * 8;
    }
    const int awoff = ((arow >> 4) * 64 + (arow & 15) + ks * 16) * 16;  // byte

    const int cr = lane >> 4;        // epilogue row group
    const int cc = lane & 15;        // epilogue col

    f32x4 acc[8][4] = {};            // 8 N-frags x 4 M-frags

    // ---- prologue: UV(0) loads, DMA(0)->Bs[0], DMA(1)->Bs[1], build A(0)
    {
        f32x4 u0 = ((const f32x4*)uptrA)[0], u1 = ((const f32x4*)uptrA)[1];
        f32x4 v0 = ((const f32x4*)vptrA)[0], v1 = ((const f32x4*)vptrA)[1];

        const char* gs = (const char*)W2r + t * 16;
#pragma unroll
        for (int q = 0; q < 4; ++q)
            async_lds16(gs + q * 8192, &Bs[0][0] + q * 8192 + wave * 1024);
        gs += 32768;
#pragma unroll
        for (int q = 0; q < 4; ++q)
            async_lds16(gs + q * 8192, &Bs[1][0] + q * 8192 + wave * 1024);

        f32x4 h0, h1;
#pragma unroll
        for (int q = 0; q < 4; ++q) {
            h0[q] = fmaxf(u0[q] + v0[q], 0.0f);
            h1[q] = fmaxf(u1[q] + v1[q], 0.0f);
        }
        u32x4 P;
        P[0] = cvt2_bf16(h0[0], h0[1]); P[1] = cvt2_bf16(h0[2], h0[3]);
        P[2] = cvt2_bf16(h1[0], h1[1]); P[3] = cvt2_bf16(h1[2], h1[3]);
        *(u32x4*)(&As[0][0] + awoff) = P;
        asm volatile("s_waitcnt lgkmcnt(0)" ::: "memory");
    }

    int rd3 = 0;    // g % 3  (MFMA B buffer)
    int wr3 = 2;    // (g+2) % 3  (DMA dest buffer)

#pragma unroll 1
    for (int g = 0; g < 32; ++g) {
        // DMA(g) completeness: for g==0 explicit; for g>0 the A-build of
        // iter g-1 waited UV(g) (issued after DMA(g)) -> DMA(g) drained.
        if (g == 0) asm volatile("s_waitcnt vmcnt(4)" ::: "memory");
        __builtin_amdgcn_s_barrier();
        asm volatile("" ::: "memory");

        // ---- issue next-step loads; they stay in flight across barriers
        f32x4 u0, u1, v0, v1;
        if (g < 31) {
            const int gn = g + 1;
            const float* up = ((gn & 16) ? uptrB : uptrA) + (gn & 15) * 32;
            const float* vp = ((gn & 16) ? vptrB : vptrA) + (gn & 15) * 32;
            u0 = ((const f32x4*)up)[0]; u1 = ((const f32x4*)up)[1];
            v0 = ((const f32x4*)vp)[0]; v1 = ((const f32x4*)vp)[1];
        }
        if (g < 30) {
            const char* gs = (const char*)W2r + ((g + 2) & 15) * 32768 + t * 16;
            char* ld = (char*)&Bs[wr3][0] + wave * 1024;
#pragma unroll
            for (int q = 0; q < 4; ++q)
                async_lds16(gs + q * 8192, ld + q * 8192);
        }
        asm volatile("" ::: "memory");

        // ---- MFMA on As[g&1], Bs[g%3] (fragment-major, lane-linear reads)
        {
            const unsigned char* aB = &As[g & 1][0];
            const unsigned char* bB = &Bs[rd3][0];
            bf16x8 af[4], bfr[8];
#pragma unroll
            for (int m = 0; m < 4; ++m)
                af[m] = *(const bf16x8*)(aB + (wr * 4 + m) * 1024 + lane * 16);
#pragma unroll
            for (int n = 0; n < 8; ++n)
                bfr[n] = *(const bf16x8*)(bB + (wc * 8 + n) * 1024 + lane * 16);
            __builtin_amdgcn_s_setprio(1);
#pragma unroll
            for (int n = 0; n < 8; ++n)
#pragma unroll
                for (int m = 0; m < 4; ++m)
                    acc[n][m] = __builtin_amdgcn_mfma_f32_16x16x32_bf16(
                        af[m], bfr[n], acc[n][m], 0, 0, 0);
            __builtin_amdgcn_s_setprio(0);
        }

        // ---- build A(g+1): relu/cvt -> frag-major ds_write into As[(g+1)&1]
        // (UV consume here emits vmcnt(4) -> proves DMA(g+1) complete)
        if (g < 31) {
            f32x4 h0, h1;
#pragma unroll
            for (int q = 0; q < 4; ++q) {
                h0[q] = fmaxf(u0[q] + v0[q], 0.0f);
                h1[q] = fmaxf(u1[q] + v1[q], 0.0f);
            }
            u32x4 P;
            P[0] = cvt2_bf16(h0[0], h0[1]); P[1] = cvt2_bf16(h0[2], h0[3]);
            P[2] = cvt2_bf16(h1[0], h1[1]); P[3] = cvt2_bf16(h1[2], h1[3]);
            *(u32x4*)(&As[(g + 1) & 1][0] + awoff) = P;
        }

        // ---- tile0 epilogue between segments: issue stores, zero acc.
        // HBM drain overlaps tile1's 16 compute steps.
        if (g == 15) {
#pragma unroll
            for (int n = 0; n < 8; ++n) {
                int col = wc * 128 + n * 16 + cc;
                float bias = b2[col];
#pragma unroll
                for (int m = 0; m < 4; ++m) {
                    int rowb = m0A + wr * 64 + m * 16 + cr * 4;
#pragma unroll
                    for (int r_ = 0; r_ < 4; ++r_)
                        out[(size_t)(rowb + r_) * 512 + col] = acc[n][m][r_] + bias;
#pragma unroll
                    for (int r_ = 0; r_ < 4; ++r_) acc[n][m][r_] = 0.0f;
                }
            }
        }

        asm volatile("s_waitcnt lgkmcnt(0)" ::: "memory");
        rd3 = (rd3 == 2) ? 0 : rd3 + 1;
        wr3 = (wr3 == 2) ? 0 : wr3 + 1;
    }

    // ---- tile1 epilogue
#pragma unroll
    for (int n = 0; n < 8; ++n) {
        int col = wc * 128 + n * 16 + cc;
        float bias = b2[col];
#pragma unroll
        for (int m = 0; m < 4; ++m) {
            int rowb = m0B + wr * 64 + m * 16 + cr * 4;
#pragma unroll
            for (int r_ = 0; r_ < 4; ++r_)
                out[(size_t)(rowb + r_) * 512 + col] = acc[n][m][r_] + bias;
        }
    }
}

// ---------------------------------------------------------------------------
extern "C" void kernel_launch(void* const* d_in, const int* in_sizes, int n_in,
                              void* d_out, int out_size, void* d_ws, size_t ws_size,
                              hipStream_t stream) {
    const float* pf = (const float*)d_in[0];   // (64, 32, 512)
    const float* W1 = (const float*)d_in[1];   // (512, 1024)
    const float* b1 = (const float*)d_in[2];   // (512,)
    const float* W2 = (const float*)d_in[3];   // (512, 512)
    const float* b2 = (const float*)d_in[4];   // (512,)
    float* out = (float*)d_out;                // (64, 992, 512)

    float* UV = (float*)d_ws;                                       // 8 MB
    unsigned short* W2r = (unsigned short*)((char*)d_ws + (size_t)8 * 1024 * 1024); // 512 KB

    prep<<<dim3(384), dim3(256), 0, stream>>>(pf, W1, b1, W2, UV, W2r);
    fused_gemm<<<dim3(248), dim3(512), 0, stream>>>(UV, W2r, b2, out);
}